// Round 3
// baseline (598.139 us; speedup 1.0000x reference)
//
#include <hip/hip_runtime.h>
#include <hip/hip_bf16.h>
#include <stdint.h>
#include <type_traits>

typedef unsigned short ushort_t;
typedef __bf16 bf16x8 __attribute__((ext_vector_type(8)));
typedef unsigned short u16x8 __attribute__((ext_vector_type(8)));
typedef float f32x4 __attribute__((ext_vector_type(4)));

#define MFMA_BF16(a, b, c) __builtin_amdgcn_mfma_f32_16x16x32_bf16((a), (b), (c), 0, 0, 0)

#define GLD_LDS(gptr, lptr) \
    __builtin_amdgcn_global_load_lds((const __attribute__((address_space(1))) void*)(gptr), \
                                     (__attribute__((address_space(3))) void*)(lptr), 16, 0, 0)

static __device__ __forceinline__ float bf2f(__hip_bfloat16 x) { return __bfloat162float(x); }
static __device__ __forceinline__ ushort_t f2bfbits(float f) {
    __hip_bfloat16 h = __float2bfloat16(f);
    return *(ushort_t*)&h;
}

template <typename T>
static __device__ __forceinline__ void storeT(T* p, float v);
template <>
__device__ __forceinline__ void storeT<float>(float* p, float v) { *p = v; }
template <>
__device__ __forceinline__ void storeT<__hip_bfloat16>(__hip_bfloat16* p, float v) {
    *p = __float2bfloat16(v);
}

// ---------------------------------------------------------------------------
// dtype probe (insurance): bf16 N(0,1) data has exponent field <= ~0x82;
// fp32 low halves reinterpreted as bf16 have ~uniform exponent -> ~25% >= 0xC0.
// Pre-converts slopes + biases to float.
// ---------------------------------------------------------------------------
__global__ void detect_kernel(const ushort_t* __restrict__ X,
                              const void* bq, const void* bk, const void* bv,
                              const void* bo, const void* slopes,
                              int* flag, float* slopesF, float* bqF,
                              float* bkF, float* bvF, float* boF) {
    __shared__ int cnt_s;
    if (threadIdx.x == 0) cnt_s = 0;
    __syncthreads();
    int cnt = 0;
    for (int i = threadIdx.x; i < 8192; i += 256) {
        ushort_t u = X[2 * i];
        int ex = (u >> 7) & 0xFF;
        if (ex >= 0xC0) cnt++;
    }
    for (int off = 1; off < 64; off <<= 1) cnt += __shfl_xor(cnt, off);
    if ((threadIdx.x & 63) == 0) atomicAdd(&cnt_s, cnt);
    __syncthreads();
    const bool f32 = cnt_s > 100;
    if (threadIdx.x == 0) *flag = f32 ? 1 : 0;
    auto conv = [&](const void* src, float* dst, int n) {
        for (int i = threadIdx.x; i < n; i += 256)
            dst[i] = f32 ? ((const float*)src)[i]
                         : __bfloat162float(((const __hip_bfloat16*)src)[i]);
    };
    conv(bq, bqF, 2048);
    conv(bk, bkF, 512);
    conv(bv, bvF, 512);
    conv(bo, boF, 2048);
    conv(slopes, slopesF, 32);
}

// ---------------------------------------------------------------------------
// Tile staging into bf16 LDS [128][64] row-major.
// ---------------------------------------------------------------------------
__device__ __forceinline__ void stage_tile(const __hip_bfloat16* __restrict__ M, int K,
                                           int k0, ushort_t* lds, int tid) {
    const int wave = tid >> 6, lane = tid & 63;
    const int srow = lane >> 3;
    const int scol = (lane & 7) * 8;
#pragma unroll
    for (int t = 0; t < 4; ++t) {
        const int chunk = wave * 4 + t;  // 16 chunks x 8 rows
        GLD_LDS((const ushort_t*)M + (size_t)(chunk * 8 + srow) * K + k0 + scol,
                lds + chunk * 512);
    }
}

__device__ __forceinline__ void stage_tile(const float* __restrict__ M, int K,
                                           int k0, ushort_t* lds, int tid) {
#pragma unroll
    for (int q = 0; q < 8; ++q) {
        const int idx = q * 256 + tid;   // 0..2047 float4s
        const int row = idx >> 4;
        const int c4 = (idx & 15) * 4;
        float4 f = *(const float4*)(M + (size_t)row * K + k0 + c4);
        *(ushort4*)(lds + row * 64 + c4) =
            make_ushort4(f2bfbits(f.x), f2bfbits(f.y), f2bfbits(f.z), f2bfbits(f.w));
    }
}

// ---------------------------------------------------------------------------
// 128x128xK GEMM tile: C[128][128] = A[128][K] * W[128][K]^T + biasF
// 256 threads = 4 waves (2x2 of 64x64 sub-tiles), 16x16x32 bf16 MFMA.
// ---------------------------------------------------------------------------
template <typename TA, typename TW, typename TC>
__device__ __forceinline__ void gemm_tile(const TA* __restrict__ A,
                                          const TW* __restrict__ W,
                                          const float* __restrict__ biasF,
                                          TC* __restrict__ C, int K, int ldc) {
    __shared__ __align__(16) ushort_t As[128 * 64];
    __shared__ __align__(16) ushort_t Bs[128 * 64];
    const int tid = threadIdx.x;
    const int wave = tid >> 6, lane = tid & 63;
    const int quad = lane >> 4, l15 = lane & 15;
    const int wm = (wave >> 1) * 64, wn = (wave & 1) * 64;

    f32x4 acc[4][4];
#pragma unroll
    for (int i = 0; i < 4; ++i)
#pragma unroll
        for (int j = 0; j < 4; ++j) acc[i][j] = {0.f, 0.f, 0.f, 0.f};

    for (int k0 = 0; k0 < K; k0 += 64) {
        stage_tile(A, K, k0, As, tid);
        stage_tile(W, K, k0, Bs, tid);
        __syncthreads();
#pragma unroll
        for (int kk = 0; kk < 2; ++kk) {
            bf16x8 af[4], bfr[4];
#pragma unroll
            for (int mi = 0; mi < 4; ++mi)
                af[mi] = *(const bf16x8*)(As + (wm + mi * 16 + l15) * 64 + kk * 32 + quad * 8);
#pragma unroll
            for (int ni = 0; ni < 4; ++ni)
                bfr[ni] = *(const bf16x8*)(Bs + (wn + ni * 16 + l15) * 64 + kk * 32 + quad * 8);
#pragma unroll
            for (int mi = 0; mi < 4; ++mi)
#pragma unroll
                for (int ni = 0; ni < 4; ++ni)
                    acc[mi][ni] = MFMA_BF16(af[mi], bfr[ni], acc[mi][ni]);
        }
        __syncthreads();
    }
#pragma unroll
    for (int mi = 0; mi < 4; ++mi) {
#pragma unroll
        for (int ni = 0; ni < 4; ++ni) {
            const int col = wn + ni * 16 + l15;
            const float bv = biasF[col];
#pragma unroll
            for (int r = 0; r < 4; ++r) {
                const int row = wm + mi * 16 + quad * 4 + r;
                storeT(C + (size_t)row * ldc + col, acc[mi][ni][r] + bv);
            }
        }
    }
}

// Fused QKV projection: grid (24, 32). nt 0..15 -> Q, 16..19 -> K, 20..23 -> V
template <bool F32>
__global__ __launch_bounds__(256, 2) void qkv_kernel(
    const int* __restrict__ flag, const void* __restrict__ Xv,
    const void* __restrict__ Wqv, const void* __restrict__ Wkv,
    const void* __restrict__ Wvv, const float* __restrict__ bqF,
    const float* __restrict__ bkF, const float* __restrict__ bvF,
    __hip_bfloat16* __restrict__ Qb, __hip_bfloat16* __restrict__ Kb,
    __hip_bfloat16* __restrict__ Vb) {
    if ((*flag == 1) != F32) return;
    using T = typename std::conditional<F32, float, __hip_bfloat16>::type;
    const T* X = (const T*)Xv;
    const int nt = blockIdx.x, mt = blockIdx.y;
    const T* W;
    const float* bias;
    __hip_bfloat16* C;
    int ldc, colbase;
    if (nt < 16)      { W = (const T*)Wqv; bias = bqF; C = Qb; ldc = 2048; colbase = nt * 128; }
    else if (nt < 20) { W = (const T*)Wkv; bias = bkF; C = Kb; ldc = 512;  colbase = (nt - 16) * 128; }
    else              { W = (const T*)Wvv; bias = bvF; C = Vb; ldc = 512;  colbase = (nt - 20) * 128; }
    gemm_tile(X + (size_t)mt * 128 * 2048, W + (size_t)colbase * 2048, bias + colbase,
              C + (size_t)mt * 128 * ldc + colbase, 2048, ldc);
}

// Output projection: grid (16, 32). A (attention out, bf16 ws) x Wo -> fp32 d_out.
template <bool F32>
__global__ __launch_bounds__(256, 2) void oproj_kernel(
    const int* __restrict__ flag, const __hip_bfloat16* __restrict__ A,
    const void* __restrict__ Wov, const float* __restrict__ boF,
    float* __restrict__ C) {
    if ((*flag == 1) != F32) return;
    using T = typename std::conditional<F32, float, __hip_bfloat16>::type;
    gemm_tile(A + (size_t)blockIdx.y * 128 * 2048,
              (const T*)Wov + (size_t)blockIdx.x * 128 * 2048, boF + blockIdx.x * 128,
              C + (size_t)blockIdx.y * 128 * 2048 + blockIdx.x * 128, 2048, 2048);
}

// ---------------------------------------------------------------------------
// Flash attention with ALiBi + causal + sliding window(1024). One block per
// (b, h, 64-row q-tile). 4 waves; each wave owns 16 q-rows. All I/O bf16 (ws).
// ---------------------------------------------------------------------------
__global__ __launch_bounds__(256, 2) void attn_kernel(
    const __hip_bfloat16* __restrict__ Qg, const __hip_bfloat16* __restrict__ Kg,
    const __hip_bfloat16* __restrict__ Vg, const float* __restrict__ slopesF,
    __hip_bfloat16* __restrict__ Og) {
    constexpr int S = 2048, WIN = 1024;
    constexpr float SCALE = 0.125f;
    constexpr float LOG2E = 1.44269504f;
    __shared__ __align__(16) ushort_t P_lds[64 * 72];
    __shared__ __align__(16) ushort_t Vt[64 * 72];  // V^T: [dh][j], stride 72

    const int tile = blockIdx.x;
    const int qt = tile & 31;
    const int h = (tile >> 5) & 31;
    const int b = tile >> 10;
    const int i0 = qt * 64;
    const int hkv = h >> 2;
    const int tid = threadIdx.x;
    const int wave = tid >> 6, lane = tid & 63;
    const int quad = lane >> 4, l15 = lane & 15;
    const float slope = slopesF[h];

    const int qrow = i0 + wave * 16 + l15;
    const __hip_bfloat16* qbase = Qg + ((size_t)(b * S + qrow)) * 2048 + h * 64;
    bf16x8 aq[2];
    aq[0] = *(const bf16x8*)(qbase + quad * 8);
    aq[1] = *(const bf16x8*)(qbase + 32 + quad * 8);

    f32x4 oacc[4];
#pragma unroll
    for (int ni = 0; ni < 4; ++ni) oacc[ni] = {0.f, 0.f, 0.f, 0.f};
    float m_i[4], l_i[4];
#pragma unroll
    for (int r = 0; r < 4; ++r) { m_i[r] = -1e30f; l_i[r] = 0.f; }

    const int jt_lo = (i0 - WIN + 1) > 0 ? ((i0 - WIN + 1) >> 6) : 0;
    for (int jt = jt_lo; jt <= qt; ++jt) {
        const int j0 = jt * 64;
#pragma unroll
        for (int it = 0; it < 2; ++it) {
            const int j = it * 32 + (tid >> 3);
            const int dh0 = (tid & 7) * 8;
            u16x8 vv = *(const u16x8*)(Vg + ((size_t)(b * S + j0 + j)) * 512 + hkv * 64 + dh0);
#pragma unroll
            for (int e = 0; e < 8; ++e) Vt[(dh0 + e) * 72 + j] = vv[e];
        }
        f32x4 sacc[4];
#pragma unroll
        for (int ni = 0; ni < 4; ++ni) sacc[ni] = {0.f, 0.f, 0.f, 0.f};
#pragma unroll
        for (int kk = 0; kk < 2; ++kk) {
#pragma unroll
            for (int ni = 0; ni < 4; ++ni) {
                bf16x8 bkf = *(const bf16x8*)(Kg + ((size_t)(b * S + j0 + ni * 16 + l15)) * 512 +
                                              hkv * 64 + kk * 32 + quad * 8);
                sacc[ni] = MFMA_BF16(aq[kk], bkf, sacc[ni]);
            }
        }
#pragma unroll
        for (int r = 0; r < 4; ++r) {
            const int i = i0 + wave * 16 + quad * 4 + r;
            float sv[4];
            float rowmax = -1e30f;
#pragma unroll
            for (int ni = 0; ni < 4; ++ni) {
                const int j = j0 + ni * 16 + l15;
                float s = sacc[ni][r] * SCALE + slope * (float)(j - i);
                const bool valid = (j <= i) && ((i - j) < WIN);
                s = valid ? s : -1e30f;
                sv[ni] = s;
                rowmax = fmaxf(rowmax, s);
            }
#pragma unroll
            for (int off = 1; off < 16; off <<= 1)
                rowmax = fmaxf(rowmax, __shfl_xor(rowmax, off));
            const float mn = fmaxf(m_i[r], rowmax);
            const float alpha = exp2f((m_i[r] - mn) * LOG2E);
            float rowsum = 0.f;
#pragma unroll
            for (int ni = 0; ni < 4; ++ni) {
                const float p = (sv[ni] > -1e29f) ? exp2f((sv[ni] - mn) * LOG2E) : 0.f;
                P_lds[(wave * 16 + quad * 4 + r) * 72 + ni * 16 + l15] = f2bfbits(p);
                rowsum += p;
            }
#pragma unroll
            for (int off = 1; off < 16; off <<= 1) rowsum += __shfl_xor(rowsum, off);
            l_i[r] = l_i[r] * alpha + rowsum;
            m_i[r] = mn;
#pragma unroll
            for (int ni = 0; ni < 4; ++ni) oacc[ni][r] *= alpha;
        }
        __syncthreads();
#pragma unroll
        for (int kk = 0; kk < 2; ++kk) {
            bf16x8 ap = *(const bf16x8*)(P_lds + (wave * 16 + l15) * 72 + kk * 32 + quad * 8);
#pragma unroll
            for (int ni = 0; ni < 4; ++ni) {
                bf16x8 bvf = *(const bf16x8*)(Vt + (ni * 16 + l15) * 72 + kk * 32 + quad * 8);
                oacc[ni] = MFMA_BF16(ap, bvf, oacc[ni]);
            }
        }
        __syncthreads();
    }
#pragma unroll
    for (int ni = 0; ni < 4; ++ni) {
#pragma unroll
        for (int r = 0; r < 4; ++r) {
            const int srow = i0 + wave * 16 + quad * 4 + r;
            const float v = oacc[ni][r] / l_i[r];
            Og[((size_t)(b * S + srow)) * 2048 + h * 64 + ni * 16 + l15] = __float2bfloat16(v);
        }
    }
}

extern "C" void kernel_launch(void* const* d_in, const int* in_sizes, int n_in,
                              void* d_out, int out_size, void* d_ws, size_t ws_size,
                              hipStream_t stream) {
    (void)in_sizes; (void)n_in; (void)out_size; (void)ws_size;
    const void* X  = d_in[0];
    const void* Wq = d_in[1];
    const void* bq = d_in[2];
    const void* Wk = d_in[3];
    const void* bk = d_in[4];
    const void* Wv = d_in[5];
    const void* bv = d_in[6];
    const void* Wo = d_in[7];
    const void* bo = d_in[8];
    const void* sl = d_in[9];
    float* outp = (float*)d_out;  // reference output dtype is float32

    char* ws = (char*)d_ws;
    const size_t MB = 1024 * 1024;
    __hip_bfloat16* Qb = (__hip_bfloat16*)(ws);            // 16 MB
    __hip_bfloat16* Kb = (__hip_bfloat16*)(ws + 16 * MB);  //  4 MB
    __hip_bfloat16* Vb = (__hip_bfloat16*)(ws + 20 * MB);  //  4 MB
    __hip_bfloat16* Ab = (__hip_bfloat16*)(ws + 24 * MB);  // 16 MB
    int*   flag    = (int*)(ws + 40 * MB);
    float* slopesF = (float*)(ws + 40 * MB + 1024);
    float* bqF     = (float*)(ws + 40 * MB + 4096);
    float* bkF     = bqF + 2048;
    float* bvF     = bkF + 512;
    float* boF     = bvF + 512;

    detect_kernel<<<1, 256, 0, stream>>>((const ushort_t*)X, bq, bk, bv, bo, sl,
                                         flag, slopesF, bqF, bkF, bvF, boF);
    qkv_kernel<false><<<dim3(24, 32), 256, 0, stream>>>(flag, X, Wq, Wk, Wv, bqF, bkF, bvF,
                                                        Qb, Kb, Vb);
    qkv_kernel<true><<<dim3(24, 32), 256, 0, stream>>>(flag, X, Wq, Wk, Wv, bqF, bkF, bvF,
                                                       Qb, Kb, Vb);
    attn_kernel<<<dim3(2048), 256, 0, stream>>>(Qb, Kb, Vb, slopesF, Ab);
    oproj_kernel<false><<<dim3(16, 32), 256, 0, stream>>>(flag, Ab, Wo, boF, outp);
    oproj_kernel<true><<<dim3(16, 32), 256, 0, stream>>>(flag, Ab, Wo, boF, outp);
}

// Round 4
// 441.903 us; speedup vs baseline: 1.3536x; 1.3536x over previous
//
#include <hip/hip_runtime.h>
#include <hip/hip_bf16.h>
#include <stdint.h>
#include <type_traits>

typedef unsigned short ushort_t;
typedef __bf16 bf16x8 __attribute__((ext_vector_type(8)));
typedef unsigned short u16x8 __attribute__((ext_vector_type(8)));
typedef float f32x4 __attribute__((ext_vector_type(4)));

#define MFMA_BF16(a, b, c) __builtin_amdgcn_mfma_f32_16x16x32_bf16((a), (b), (c), 0, 0, 0)

#define GLD_LDS(gptr, lptr) \
    __builtin_amdgcn_global_load_lds((const __attribute__((address_space(1))) void*)(gptr), \
                                     (__attribute__((address_space(3))) void*)(lptr), 16, 0, 0)

static __device__ __forceinline__ float bf2f(__hip_bfloat16 x) { return __bfloat162float(x); }
static __device__ __forceinline__ ushort_t f2bfbits(float f) {
    __hip_bfloat16 h = __float2bfloat16(f);
    return *(ushort_t*)&h;
}

template <typename T>
static __device__ __forceinline__ void storeT(T* p, float v);
template <>
__device__ __forceinline__ void storeT<float>(float* p, float v) { *p = v; }
template <>
__device__ __forceinline__ void storeT<__hip_bfloat16>(__hip_bfloat16* p, float v) {
    *p = __float2bfloat16(v);
}

// ---------------------------------------------------------------------------
// dtype probe: fp32 low halves reinterpreted as bf16 have ~25% exponent>=0xC0;
// true bf16 N(0,1) never does. Pre-converts slopes + biases to float.
// ---------------------------------------------------------------------------
__global__ void detect_kernel(const ushort_t* __restrict__ X,
                              const void* bq, const void* bk, const void* bv,
                              const void* bo, const void* slopes,
                              int* flag, float* slopesF, float* bqF,
                              float* bkF, float* bvF, float* boF) {
    __shared__ int cnt_s;
    if (threadIdx.x == 0) cnt_s = 0;
    __syncthreads();
    int cnt = 0;
    for (int i = threadIdx.x; i < 8192; i += 256) {
        ushort_t u = X[2 * i];
        int ex = (u >> 7) & 0xFF;
        if (ex >= 0xC0) cnt++;
    }
    for (int off = 1; off < 64; off <<= 1) cnt += __shfl_xor(cnt, off);
    if ((threadIdx.x & 63) == 0) atomicAdd(&cnt_s, cnt);
    __syncthreads();
    const bool f32 = cnt_s > 100;
    if (threadIdx.x == 0) *flag = f32 ? 1 : 0;
    auto conv = [&](const void* src, float* dst, int n) {
        for (int i = threadIdx.x; i < n; i += 256)
            dst[i] = f32 ? ((const float*)src)[i]
                         : __bfloat162float(((const __hip_bfloat16*)src)[i]);
    };
    conv(bq, bqF, 2048);
    conv(bk, bkF, 512);
    conv(bv, bvF, 512);
    conv(bo, boF, 2048);
    conv(slopes, slopesF, 32);
}

// ---------------------------------------------------------------------------
// Bulk dtype convert: n4 groups of 4 elements. fp32: float4 -> bf16x4.
// bf16: straight 8B copy. Memory-bound, ~6 TB/s.
// ---------------------------------------------------------------------------
__global__ __launch_bounds__(256) void cvt_kernel(const int* __restrict__ flag,
                                                  const void* __restrict__ src,
                                                  ushort_t* __restrict__ dst, int n4) {
    const bool f32 = (*flag == 1);
    const int stride = gridDim.x * 256;
    for (int i = blockIdx.x * 256 + threadIdx.x; i < n4; i += stride) {
        if (f32) {
            float4 f = ((const float4*)src)[i];
            ((ushort4*)dst)[i] =
                make_ushort4(f2bfbits(f.x), f2bfbits(f.y), f2bfbits(f.z), f2bfbits(f.w));
        } else {
            ((ushort4*)dst)[i] = ((const ushort4*)src)[i];
        }
    }
}

// ---------------------------------------------------------------------------
// Tile staging into bf16 LDS [128][64] row-major.
// ---------------------------------------------------------------------------
__device__ __forceinline__ void stage_tile(const __hip_bfloat16* __restrict__ M, int K,
                                           int k0, ushort_t* lds, int tid) {
    const int wave = tid >> 6, lane = tid & 63;
    const int srow = lane >> 3;
    const int scol = (lane & 7) * 8;
#pragma unroll
    for (int t = 0; t < 4; ++t) {
        const int chunk = wave * 4 + t;  // 16 chunks x 8 rows
        GLD_LDS((const ushort_t*)M + (size_t)(chunk * 8 + srow) * K + k0 + scol,
                lds + chunk * 512);
    }
}

__device__ __forceinline__ void stage_tile(const float* __restrict__ M, int K,
                                           int k0, ushort_t* lds, int tid) {
#pragma unroll
    for (int q = 0; q < 8; ++q) {
        const int idx = q * 256 + tid;   // 0..2047 float4s
        const int row = idx >> 4;
        const int c4 = (idx & 15) * 4;
        float4 f = *(const float4*)(M + (size_t)row * K + k0 + c4);
        *(ushort4*)(lds + row * 64 + c4) =
            make_ushort4(f2bfbits(f.x), f2bfbits(f.y), f2bfbits(f.z), f2bfbits(f.w));
    }
}

// ---------------------------------------------------------------------------
// 128x128xK GEMM tile: C[128][128] = A[128][K] * W[128][K]^T + biasF
// 256 threads = 4 waves (2x2 of 64x64 sub-tiles), 16x16x32 bf16 MFMA.
// ---------------------------------------------------------------------------
template <typename TA, typename TW, typename TC>
__device__ __forceinline__ void gemm_tile(const TA* __restrict__ A,
                                          const TW* __restrict__ W,
                                          const float* __restrict__ biasF,
                                          TC* __restrict__ C, int K, int ldc) {
    __shared__ __align__(16) ushort_t As[128 * 64];
    __shared__ __align__(16) ushort_t Bs[128 * 64];
    const int tid = threadIdx.x;
    const int wave = tid >> 6, lane = tid & 63;
    const int quad = lane >> 4, l15 = lane & 15;
    const int wm = (wave >> 1) * 64, wn = (wave & 1) * 64;

    f32x4 acc[4][4];
#pragma unroll
    for (int i = 0; i < 4; ++i)
#pragma unroll
        for (int j = 0; j < 4; ++j) acc[i][j] = {0.f, 0.f, 0.f, 0.f};

    for (int k0 = 0; k0 < K; k0 += 64) {
        stage_tile(A, K, k0, As, tid);
        stage_tile(W, K, k0, Bs, tid);
        __syncthreads();
#pragma unroll
        for (int kk = 0; kk < 2; ++kk) {
            bf16x8 af[4], bfr[4];
#pragma unroll
            for (int mi = 0; mi < 4; ++mi)
                af[mi] = *(const bf16x8*)(As + (wm + mi * 16 + l15) * 64 + kk * 32 + quad * 8);
#pragma unroll
            for (int ni = 0; ni < 4; ++ni)
                bfr[ni] = *(const bf16x8*)(Bs + (wn + ni * 16 + l15) * 64 + kk * 32 + quad * 8);
#pragma unroll
            for (int mi = 0; mi < 4; ++mi)
#pragma unroll
                for (int ni = 0; ni < 4; ++ni)
                    acc[mi][ni] = MFMA_BF16(af[mi], bfr[ni], acc[mi][ni]);
        }
        __syncthreads();
    }
#pragma unroll
    for (int mi = 0; mi < 4; ++mi) {
#pragma unroll
        for (int ni = 0; ni < 4; ++ni) {
            const int col = wn + ni * 16 + l15;
            const float bv = biasF[col];
#pragma unroll
            for (int r = 0; r < 4; ++r) {
                const int row = wm + mi * 16 + quad * 4 + r;
                storeT(C + (size_t)row * ldc + col, acc[mi][ni][r] + bv);
            }
        }
    }
}

// ======================== FAST PATH (pure-bf16 GEMMs) =======================
// Fused QKV projection: grid (24, 32). nt 0..15 -> Q, 16..19 -> K, 20..23 -> V
__global__ __launch_bounds__(256, 2) void qkv_fast(
    const __hip_bfloat16* __restrict__ X,
    const __hip_bfloat16* __restrict__ Wq, const __hip_bfloat16* __restrict__ Wk,
    const __hip_bfloat16* __restrict__ Wv, const float* __restrict__ bqF,
    const float* __restrict__ bkF, const float* __restrict__ bvF,
    __hip_bfloat16* __restrict__ Qb, __hip_bfloat16* __restrict__ Kb,
    __hip_bfloat16* __restrict__ Vb) {
    const int nt = blockIdx.x, mt = blockIdx.y;
    const __hip_bfloat16* W;
    const float* bias;
    __hip_bfloat16* C;
    int ldc, colbase;
    if (nt < 16)      { W = Wq; bias = bqF; C = Qb; ldc = 2048; colbase = nt * 128; }
    else if (nt < 20) { W = Wk; bias = bkF; C = Kb; ldc = 512;  colbase = (nt - 16) * 128; }
    else              { W = Wv; bias = bvF; C = Vb; ldc = 512;  colbase = (nt - 20) * 128; }
    gemm_tile(X + (size_t)mt * 128 * 2048, W + (size_t)colbase * 2048, bias + colbase,
              C + (size_t)mt * 128 * ldc + colbase, 2048, ldc);
}

__global__ __launch_bounds__(256, 2) void oproj_fast(
    const __hip_bfloat16* __restrict__ A, const __hip_bfloat16* __restrict__ Wo,
    const float* __restrict__ boF, float* __restrict__ C) {
    gemm_tile(A + (size_t)blockIdx.y * 128 * 2048,
              Wo + (size_t)blockIdx.x * 128 * 2048, boF + blockIdx.x * 128,
              C + (size_t)blockIdx.y * 128 * 2048 + blockIdx.x * 128, 2048, 2048);
}

// ==================== FALLBACK PATH (round-3, ws < 56 MB) ===================
template <bool F32>
__global__ __launch_bounds__(256, 2) void qkv_kernel(
    const int* __restrict__ flag, const void* __restrict__ Xv,
    const void* __restrict__ Wqv, const void* __restrict__ Wkv,
    const void* __restrict__ Wvv, const float* __restrict__ bqF,
    const float* __restrict__ bkF, const float* __restrict__ bvF,
    __hip_bfloat16* __restrict__ Qb, __hip_bfloat16* __restrict__ Kb,
    __hip_bfloat16* __restrict__ Vb) {
    if ((*flag == 1) != F32) return;
    using T = typename std::conditional<F32, float, __hip_bfloat16>::type;
    const T* X = (const T*)Xv;
    const int nt = blockIdx.x, mt = blockIdx.y;
    const T* W;
    const float* bias;
    __hip_bfloat16* C;
    int ldc, colbase;
    if (nt < 16)      { W = (const T*)Wqv; bias = bqF; C = Qb; ldc = 2048; colbase = nt * 128; }
    else if (nt < 20) { W = (const T*)Wkv; bias = bkF; C = Kb; ldc = 512;  colbase = (nt - 16) * 128; }
    else              { W = (const T*)Wvv; bias = bvF; C = Vb; ldc = 512;  colbase = (nt - 20) * 128; }
    gemm_tile(X + (size_t)mt * 128 * 2048, W + (size_t)colbase * 2048, bias + colbase,
              C + (size_t)mt * 128 * ldc + colbase, 2048, ldc);
}

template <bool F32>
__global__ __launch_bounds__(256, 2) void oproj_kernel(
    const int* __restrict__ flag, const __hip_bfloat16* __restrict__ A,
    const void* __restrict__ Wov, const float* __restrict__ boF,
    float* __restrict__ C) {
    if ((*flag == 1) != F32) return;
    using T = typename std::conditional<F32, float, __hip_bfloat16>::type;
    gemm_tile(A + (size_t)blockIdx.y * 128 * 2048,
              (const T*)Wov + (size_t)blockIdx.x * 128 * 2048, boF + blockIdx.x * 128,
              C + (size_t)blockIdx.y * 128 * 2048 + blockIdx.x * 128, 2048, 2048);
}

// ---------------------------------------------------------------------------
// Flash attention with ALiBi + causal + sliding window(1024). One block per
// (b, h, 64-row q-tile). 4 waves; each wave owns 16 q-rows. All I/O bf16 (ws).
// ---------------------------------------------------------------------------
__global__ __launch_bounds__(256, 2) void attn_kernel(
    const __hip_bfloat16* __restrict__ Qg, const __hip_bfloat16* __restrict__ Kg,
    const __hip_bfloat16* __restrict__ Vg, const float* __restrict__ slopesF,
    __hip_bfloat16* __restrict__ Og) {
    constexpr int S = 2048, WIN = 1024;
    constexpr float SCALE = 0.125f;
    constexpr float LOG2E = 1.44269504f;
    __shared__ __align__(16) ushort_t P_lds[64 * 72];
    __shared__ __align__(16) ushort_t Vt[64 * 72];  // V^T: [dh][j], stride 72

    const int tile = blockIdx.x;
    const int qt = tile & 31;
    const int h = (tile >> 5) & 31;
    const int b = tile >> 10;
    const int i0 = qt * 64;
    const int hkv = h >> 2;
    const int tid = threadIdx.x;
    const int wave = tid >> 6, lane = tid & 63;
    const int quad = lane >> 4, l15 = lane & 15;
    const float slope = slopesF[h];

    const int qrow = i0 + wave * 16 + l15;
    const __hip_bfloat16* qbase = Qg + ((size_t)(b * S + qrow)) * 2048 + h * 64;
    bf16x8 aq[2];
    aq[0] = *(const bf16x8*)(qbase + quad * 8);
    aq[1] = *(const bf16x8*)(qbase + 32 + quad * 8);

    f32x4 oacc[4];
#pragma unroll
    for (int ni = 0; ni < 4; ++ni) oacc[ni] = {0.f, 0.f, 0.f, 0.f};
    float m_i[4], l_i[4];
#pragma unroll
    for (int r = 0; r < 4; ++r) { m_i[r] = -1e30f; l_i[r] = 0.f; }

    const int jt_lo = (i0 - WIN + 1) > 0 ? ((i0 - WIN + 1) >> 6) : 0;
    for (int jt = jt_lo; jt <= qt; ++jt) {
        const int j0 = jt * 64;
#pragma unroll
        for (int it = 0; it < 2; ++it) {
            const int j = it * 32 + (tid >> 3);
            const int dh0 = (tid & 7) * 8;
            u16x8 vv = *(const u16x8*)(Vg + ((size_t)(b * S + j0 + j)) * 512 + hkv * 64 + dh0);
#pragma unroll
            for (int e = 0; e < 8; ++e) Vt[(dh0 + e) * 72 + j] = vv[e];
        }
        f32x4 sacc[4];
#pragma unroll
        for (int ni = 0; ni < 4; ++ni) sacc[ni] = {0.f, 0.f, 0.f, 0.f};
#pragma unroll
        for (int kk = 0; kk < 2; ++kk) {
#pragma unroll
            for (int ni = 0; ni < 4; ++ni) {
                bf16x8 bkf = *(const bf16x8*)(Kg + ((size_t)(b * S + j0 + ni * 16 + l15)) * 512 +
                                              hkv * 64 + kk * 32 + quad * 8);
                sacc[ni] = MFMA_BF16(aq[kk], bkf, sacc[ni]);
            }
        }
#pragma unroll
        for (int r = 0; r < 4; ++r) {
            const int i = i0 + wave * 16 + quad * 4 + r;
            float sv[4];
            float rowmax = -1e30f;
#pragma unroll
            for (int ni = 0; ni < 4; ++ni) {
                const int j = j0 + ni * 16 + l15;
                float s = sacc[ni][r] * SCALE + slope * (float)(j - i);
                const bool valid = (j <= i) && ((i - j) < WIN);
                s = valid ? s : -1e30f;
                sv[ni] = s;
                rowmax = fmaxf(rowmax, s);
            }
#pragma unroll
            for (int off = 1; off < 16; off <<= 1)
                rowmax = fmaxf(rowmax, __shfl_xor(rowmax, off));
            const float mn = fmaxf(m_i[r], rowmax);
            const float alpha = exp2f((m_i[r] - mn) * LOG2E);
            float rowsum = 0.f;
#pragma unroll
            for (int ni = 0; ni < 4; ++ni) {
                const float p = (sv[ni] > -1e29f) ? exp2f((sv[ni] - mn) * LOG2E) : 0.f;
                P_lds[(wave * 16 + quad * 4 + r) * 72 + ni * 16 + l15] = f2bfbits(p);
                rowsum += p;
            }
#pragma unroll
            for (int off = 1; off < 16; off <<= 1) rowsum += __shfl_xor(rowsum, off);
            l_i[r] = l_i[r] * alpha + rowsum;
            m_i[r] = mn;
#pragma unroll
            for (int ni = 0; ni < 4; ++ni) oacc[ni][r] *= alpha;
        }
        __syncthreads();
#pragma unroll
        for (int kk = 0; kk < 2; ++kk) {
            bf16x8 ap = *(const bf16x8*)(P_lds + (wave * 16 + l15) * 72 + kk * 32 + quad * 8);
#pragma unroll
            for (int ni = 0; ni < 4; ++ni) {
                bf16x8 bvf = *(const bf16x8*)(Vt + (ni * 16 + l15) * 72 + kk * 32 + quad * 8);
                oacc[ni] = MFMA_BF16(ap, bvf, oacc[ni]);
            }
        }
        __syncthreads();
    }
#pragma unroll
    for (int ni = 0; ni < 4; ++ni) {
#pragma unroll
        for (int r = 0; r < 4; ++r) {
            const int srow = i0 + wave * 16 + quad * 4 + r;
            const float v = oacc[ni][r] / l_i[r];
            Og[((size_t)(b * S + srow)) * 2048 + h * 64 + ni * 16 + l15] = __float2bfloat16(v);
        }
    }
}

extern "C" void kernel_launch(void* const* d_in, const int* in_sizes, int n_in,
                              void* d_out, int out_size, void* d_ws, size_t ws_size,
                              hipStream_t stream) {
    (void)in_sizes; (void)n_in; (void)out_size;
    const void* X  = d_in[0];
    const void* Wq = d_in[1];
    const void* bq = d_in[2];
    const void* Wk = d_in[3];
    const void* bk = d_in[4];
    const void* Wv = d_in[5];
    const void* bv = d_in[6];
    const void* Wo = d_in[7];
    const void* bo = d_in[8];
    const void* sl = d_in[9];
    float* outp = (float*)d_out;  // reference output dtype is float32

    char* ws = (char*)d_ws;
    const size_t SZ_X  = (size_t)4096 * 2048 * 2;  // 16.78 MB
    const size_t SZ_WQ = (size_t)2048 * 2048 * 2;  //  8.39 MB
    const size_t SZ_WK = (size_t)512 * 2048 * 2;   //  2.10 MB
    const size_t SZ_Q  = SZ_X;
    const size_t SZ_K  = (size_t)4096 * 512 * 2;   //  4.19 MB
    const size_t FAST_NEED = SZ_X + SZ_WQ + 2 * SZ_WK + SZ_Q + 2 * SZ_K + 65536;

    if (ws_size >= FAST_NEED) {
        // ---- fast path: convert once, pure-bf16 async GEMMs ----
        size_t o = 0;
        __hip_bfloat16* Xb  = (__hip_bfloat16*)(ws + o); o += SZ_X;   // aliased by Ab
        __hip_bfloat16* Wqb = (__hip_bfloat16*)(ws + o); o += SZ_WQ;  // aliased by Wob
        __hip_bfloat16* Wkb = (__hip_bfloat16*)(ws + o); o += SZ_WK;
        __hip_bfloat16* Wvb = (__hip_bfloat16*)(ws + o); o += SZ_WK;
        __hip_bfloat16* Qb  = (__hip_bfloat16*)(ws + o); o += SZ_Q;
        __hip_bfloat16* Kb  = (__hip_bfloat16*)(ws + o); o += SZ_K;
        __hip_bfloat16* Vb  = (__hip_bfloat16*)(ws + o); o += SZ_K;
        __hip_bfloat16* Ab  = Xb;   // X dead after qkv_fast
        __hip_bfloat16* Wob = Wqb;  // Wq dead after qkv_fast
        int*   flag    = (int*)(ws + o);
        float* slopesF = (float*)(ws + o + 1024);
        float* bqF     = (float*)(ws + o + 4096);
        float* bkF     = bqF + 2048;
        float* bvF     = bkF + 512;
        float* boF     = bvF + 512;

        detect_kernel<<<1, 256, 0, stream>>>((const ushort_t*)X, bq, bk, bv, bo, sl,
                                             flag, slopesF, bqF, bkF, bvF, boF);
        cvt_kernel<<<2048, 256, 0, stream>>>(flag, X,  (ushort_t*)Xb,  4096 * 2048 / 4);
        cvt_kernel<<<2048, 256, 0, stream>>>(flag, Wq, (ushort_t*)Wqb, 2048 * 2048 / 4);
        cvt_kernel<<<512,  256, 0, stream>>>(flag, Wk, (ushort_t*)Wkb, 512 * 2048 / 4);
        cvt_kernel<<<512,  256, 0, stream>>>(flag, Wv, (ushort_t*)Wvb, 512 * 2048 / 4);
        qkv_fast<<<dim3(24, 32), 256, 0, stream>>>(Xb, Wqb, Wkb, Wvb, bqF, bkF, bvF,
                                                   Qb, Kb, Vb);
        cvt_kernel<<<2048, 256, 0, stream>>>(flag, Wo, (ushort_t*)Wob, 2048 * 2048 / 4);
        attn_kernel<<<dim3(2048), 256, 0, stream>>>(Qb, Kb, Vb, slopesF, Ab);
        oproj_fast<<<dim3(16, 32), 256, 0, stream>>>(Ab, Wob, boF, outp);
    } else {
        // ---- fallback: round-3 proven path (fits in ~41 MB) ----
        const size_t MB = 1024 * 1024;
        __hip_bfloat16* Qb = (__hip_bfloat16*)(ws);
        __hip_bfloat16* Kb = (__hip_bfloat16*)(ws + 16 * MB);
        __hip_bfloat16* Vb = (__hip_bfloat16*)(ws + 20 * MB);
        __hip_bfloat16* Ab = (__hip_bfloat16*)(ws + 24 * MB);
        int*   flag    = (int*)(ws + 40 * MB);
        float* slopesF = (float*)(ws + 40 * MB + 1024);
        float* bqF     = (float*)(ws + 40 * MB + 4096);
        float* bkF     = bqF + 2048;
        float* bvF     = bkF + 512;
        float* boF     = bvF + 512;

        detect_kernel<<<1, 256, 0, stream>>>((const ushort_t*)X, bq, bk, bv, bo, sl,
                                             flag, slopesF, bqF, bkF, bvF, boF);
        qkv_kernel<false><<<dim3(24, 32), 256, 0, stream>>>(flag, X, Wq, Wk, Wv,
                                                            bqF, bkF, bvF, Qb, Kb, Vb);
        qkv_kernel<true><<<dim3(24, 32), 256, 0, stream>>>(flag, X, Wq, Wk, Wv,
                                                           bqF, bkF, bvF, Qb, Kb, Vb);
        attn_kernel<<<dim3(2048), 256, 0, stream>>>(Qb, Kb, Vb, slopesF, Ab);
        oproj_kernel<false><<<dim3(16, 32), 256, 0, stream>>>(flag, Ab, Wo, boF, outp);
        oproj_kernel<true><<<dim3(16, 32), 256, 0, stream>>>(flag, Ab, Wo, boF, outp);
    }
}